// Round 5
// baseline (4253.106 us; speedup 1.0000x reference)
//
#include <hip/hip_runtime.h>
#include <hip/hip_bf16.h>

// DeBERTa layer: B=16,S=512,H=1024,NH=8,HD=128,FF=3072.
// CONFIRMED via R4 diagnostics: inputs f32 (x alloc = n*4), OUTPUT f32
// (out alloc = out_size*4), ws_size = 256 MiB. Threshold 0.107 = 8 bf16-ulps
// -> bf16 internal compute sanctioned. Intermediates bf16, fp32 accumulation.
#define BB  16
#define SS  512
#define HH  1024
#define NHH 8
#define HDD 128
#define FFF 3072
#define TT  (BB * SS)   // 8192 tokens

typedef __hip_bfloat16 bf16;

__device__ __forceinline__ float bf2f(bf16 v) { return __bfloat162float(v); }
__device__ __forceinline__ bf16 f2bf(float f) { return __float2bfloat16(f); }

// ---------------- Embedding LayerNorm: x(f32)+pos(f32) -> LN -> h(bf16) ---------
__global__ void embed_ln_kernel(const float* __restrict__ x, const float* __restrict__ pos,
                                const float* __restrict__ g, const float* __restrict__ bta,
                                bf16* __restrict__ h) {
  int t = blockIdx.x;
  int s = t & (SS - 1);
  int tid = threadIdx.x;
  const float* xr = x + (size_t)t * HH;
  const float* pr = pos + (size_t)s * HH;
  float vals[4];
  float sum = 0.f;
#pragma unroll
  for (int i = 0; i < 4; i++) {
    int c = tid + i * 256;
    vals[i] = xr[c] + pr[c];
    sum += vals[i];
  }
  __shared__ float red[4];
#pragma unroll
  for (int off = 32; off > 0; off >>= 1) sum += __shfl_down(sum, off, 64);
  if ((tid & 63) == 0) red[tid >> 6] = sum;
  __syncthreads();
  float mean = (red[0] + red[1] + red[2] + red[3]) * (1.f / HH);
  float vsum = 0.f;
#pragma unroll
  for (int i = 0; i < 4; i++) { float d = vals[i] - mean; vsum += d * d; }
  __syncthreads();
#pragma unroll
  for (int off = 32; off > 0; off >>= 1) vsum += __shfl_down(vsum, off, 64);
  if ((tid & 63) == 0) red[tid >> 6] = vsum;
  __syncthreads();
  float rstd = rsqrtf((red[0] + red[1] + red[2] + red[3]) * (1.f / HH) + 1e-7f);
  bf16* hr = h + (size_t)t * HH;
#pragma unroll
  for (int i = 0; i < 4; i++) {
    int c = tid + i * 256;
    hr[c] = f2bf((vals[i] - mean) * rstd * g[c] + bta[c]);
  }
}

// ------- a(bf16)+res(bf16) -> LN -> out (OUT_F32 ? float : bf16) ---------------
template <int OUT_F32>
__global__ void add_ln_kernel(const bf16* __restrict__ a, const bf16* __restrict__ res,
                              const float* __restrict__ g, const float* __restrict__ bta,
                              void* __restrict__ outv) {
  int t = blockIdx.x;
  int tid = threadIdx.x;
  const bf16* ar = a + (size_t)t * HH;
  const bf16* rr = res + (size_t)t * HH;
  float vals[4];
  float sum = 0.f;
#pragma unroll
  for (int i = 0; i < 4; i++) {
    int c = tid + i * 256;
    vals[i] = bf2f(ar[c]) + bf2f(rr[c]);
    sum += vals[i];
  }
  __shared__ float red[4];
#pragma unroll
  for (int off = 32; off > 0; off >>= 1) sum += __shfl_down(sum, off, 64);
  if ((tid & 63) == 0) red[tid >> 6] = sum;
  __syncthreads();
  float mean = (red[0] + red[1] + red[2] + red[3]) * (1.f / HH);
  float vsum = 0.f;
#pragma unroll
  for (int i = 0; i < 4; i++) { float d = vals[i] - mean; vsum += d * d; }
  __syncthreads();
#pragma unroll
  for (int off = 32; off > 0; off >>= 1) vsum += __shfl_down(vsum, off, 64);
  if ((tid & 63) == 0) red[tid >> 6] = vsum;
  __syncthreads();
  float rstd = rsqrtf((red[0] + red[1] + red[2] + red[3]) * (1.f / HH) + 1e-7f);
#pragma unroll
  for (int i = 0; i < 4; i++) {
    int c = tid + i * 256;
    float o = (vals[i] - mean) * rstd * g[c] + bta[c];
    if (OUT_F32)
      ((float*)outv)[(size_t)t * HH + c] = o;
    else
      ((bf16*)outv)[(size_t)t * HH + c] = f2bf(o);
  }
}

// ---- Tiled GEMM: C[M,N](bf16) = act(A[M,K](bf16) @ B[K,N](f32) + bias(f32)) ---
// 64x64 tile, 256 threads, 4x4 micro-tile, fp32 accum.
template <int GELU>
__global__ void gemm_kernel(const bf16* __restrict__ A, const float* __restrict__ Bm,
                            const float* __restrict__ bias, bf16* __restrict__ C,
                            int M, int N, int K) {
  __shared__ __align__(16) float As[16][68];  // [k][m]
  __shared__ __align__(16) float Bs[16][68];  // [k][n]
  int tid = threadIdx.x;
  int tx = tid & 15, ty = tid >> 4;
  int m0 = blockIdx.y * 64, n0 = blockIdx.x * 64;
  float acc[4][4] = {};
  for (int k0 = 0; k0 < K; k0 += 16) {
#pragma unroll
    for (int i = 0; i < 4; i++) {
      int idx = tid + i * 256;
      int r = idx >> 4, c = idx & 15;
      As[c][r] = bf2f(A[(size_t)(m0 + r) * K + k0 + c]);
      int rb = idx >> 6, cb = idx & 63;
      Bs[rb][cb] = Bm[(size_t)(k0 + rb) * N + n0 + cb];
    }
    __syncthreads();
#pragma unroll
    for (int kk = 0; kk < 16; kk++) {
      float4 av = *(const float4*)&As[kk][ty * 4];
      float4 bv = *(const float4*)&Bs[kk][tx * 4];
      float a_[4] = {av.x, av.y, av.z, av.w};
      float b_[4] = {bv.x, bv.y, bv.z, bv.w};
#pragma unroll
      for (int i = 0; i < 4; i++)
#pragma unroll
        for (int j = 0; j < 4; j++) acc[i][j] += a_[i] * b_[j];
    }
    __syncthreads();
  }
#pragma unroll
  for (int i = 0; i < 4; i++) {
    int m = m0 + ty * 4 + i;
#pragma unroll
    for (int j = 0; j < 4; j++) {
      int n = n0 + tx * 4 + j;
      float v = acc[i][j];
      if (bias) v += bias[n];
      if (GELU) v = 0.5f * v * (1.f + erff(v * 0.70710678118654752f));
      C[(size_t)m * N + n] = f2bf(v);
    }
  }
}

// ---------------- Attention: one block per (16 queries, head, batch) ------------
// q/k/v bf16 in [T,H] layout (head = 128-col slice).
__global__ void attn_kernel(const bf16* __restrict__ qb, const bf16* __restrict__ kb,
                            const bf16* __restrict__ vb, bf16* __restrict__ ctx) {
  __shared__ float qs[16][128];
  __shared__ float sc[16][513];  // +1 pad
  int tid = threadIdx.x;
  int q0 = blockIdx.x * 16;
  int hd = blockIdx.y, bt = blockIdx.z;
  size_t base = ((size_t)bt * SS) * HH + (size_t)hd * HDD;
#pragma unroll
  for (int i = 0; i < 8; i++) {
    int idx = tid + i * 256;
    int r = idx >> 7, c = idx & 127;
    qs[r][c] = bf2f(qb[base + (size_t)(q0 + r) * HH + c]) * 0.08838834764831845f;
  }
  __syncthreads();
  int gq = tid >> 4, l16 = tid & 15;
  float qreg[8];
#pragma unroll
  for (int j = 0; j < 8; j++) qreg[j] = qs[gq][l16 * 8 + j];
  for (int k = 0; k < SS; k++) {
    const bf16* kr = kb + base + (size_t)k * HH + l16 * 8;
    float p = 0.f;
#pragma unroll
    for (int j = 0; j < 8; j++) p += qreg[j] * bf2f(kr[j]);
#pragma unroll
    for (int off = 8; off > 0; off >>= 1) p += __shfl_xor(p, off, 16);
    if (l16 == 0) sc[gq][k] = p;
  }
  __syncthreads();
  float mx = -1e30f;
  for (int c = l16; c < SS; c += 16) mx = fmaxf(mx, sc[gq][c]);
#pragma unroll
  for (int off = 8; off > 0; off >>= 1) mx = fmaxf(mx, __shfl_xor(mx, off, 16));
  float sum = 0.f;
  for (int c = l16; c < SS; c += 16) {
    float e = __expf(sc[gq][c] - mx);
    sc[gq][c] = e;
    sum += e;
  }
#pragma unroll
  for (int off = 8; off > 0; off >>= 1) sum += __shfl_xor(sum, off, 16);
  float inv = 1.f / sum;
  for (int c = l16; c < SS; c += 16) sc[gq][c] *= inv;
  __syncthreads();
  int dq = tid >> 7, d = tid & 127;
  for (int pass = 0; pass < 8; pass++) {
    int ql = pass * 2 + dq;
    float acc = 0.f;
    for (int k = 0; k < SS; k++) acc += sc[ql][k] * bf2f(vb[base + (size_t)k * HH + d]);
    ctx[base + (size_t)(q0 + ql) * HH + d] = f2bf(acc);
  }
}

// ---------------- launch ----------------
extern "C" void kernel_launch(void* const* d_in, const int* in_sizes, int n_in,
                              void* d_out, int out_size, void* d_ws, size_t ws_size,
                              hipStream_t stream) {
  const float* x     = (const float*)d_in[0];
  const float* pos   = (const float*)d_in[1];
  const float* eg    = (const float*)d_in[2];
  const float* ebeta = (const float*)d_in[3];
  const float* Wq    = (const float*)d_in[4];
  const float* Wk    = (const float*)d_in[5];
  const float* Wv    = (const float*)d_in[6];
  const float* qbias = (const float*)d_in[7];
  const float* vbias = (const float*)d_in[8];
  const float* Wo    = (const float*)d_in[9];
  const float* bo    = (const float*)d_in[10];
  const float* l1g   = (const float*)d_in[11];
  const float* l1b   = (const float*)d_in[12];
  const float* Wi    = (const float*)d_in[13];
  const float* bi    = (const float*)d_in[14];
  const float* Wf    = (const float*)d_in[15];
  const float* bfb   = (const float*)d_in[16];
  const float* l2g   = (const float*)d_in[17];
  const float* l2b   = (const float*)d_in[18];

  // --- workspace: 176 MiB of fully DISJOINT buffers (ws_size = 256 MiB) ---
  char* w = (char*)d_ws;
  const size_t MB = (size_t)1 << 20;
  bf16* h    = (bf16*)(w + 0 * MB);     // [0,16)
  bf16* q    = (bf16*)(w + 16 * MB);    // [16,32)
  bf16* k    = (bf16*)(w + 32 * MB);    // [32,48)
  bf16* v    = (bf16*)(w + 48 * MB);    // [48,64)
  bf16* ctx  = (bf16*)(w + 64 * MB);    // [64,80)
  bf16* tmp1 = (bf16*)(w + 80 * MB);    // [80,96)
  bf16* attn = (bf16*)(w + 96 * MB);    // [96,112)
  bf16* ff   = (bf16*)(w + 112 * MB);   // [112,160)
  bf16* tmp2 = (bf16*)(w + 160 * MB);   // [160,176)
  float* out = (float*)d_out;           // f32! (confirmed R4: alloc = out_size*4)

  embed_ln_kernel<<<TT, 256, 0, stream>>>(x, pos, eg, ebeta, h);
  gemm_kernel<0><<<dim3(HH / 64, TT / 64), 256, 0, stream>>>(h, Wq, qbias, q, TT, HH, HH);
  gemm_kernel<0><<<dim3(HH / 64, TT / 64), 256, 0, stream>>>(h, Wk, nullptr, k, TT, HH, HH);
  gemm_kernel<0><<<dim3(HH / 64, TT / 64), 256, 0, stream>>>(h, Wv, vbias, v, TT, HH, HH);
  attn_kernel<<<dim3(SS / 16, NHH, BB), 256, 0, stream>>>(q, k, v, ctx);
  gemm_kernel<0><<<dim3(HH / 64, TT / 64), 256, 0, stream>>>(ctx, Wo, bo, tmp1, TT, HH, HH);
  add_ln_kernel<0><<<TT, 256, 0, stream>>>(tmp1, h, l1g, l1b, attn);
  gemm_kernel<1><<<dim3(FFF / 64, TT / 64), 256, 0, stream>>>(attn, Wi, bi, ff, TT, FFF, HH);
  gemm_kernel<0><<<dim3(HH / 64, TT / 64), 256, 0, stream>>>(ff, Wf, bfb, tmp2, TT, HH, FFF);
  add_ln_kernel<1><<<TT, 256, 0, stream>>>(tmp2, attn, l2g, l2b, out);
}

// Round 6
// 611.935 us; speedup vs baseline: 6.9503x; 6.9503x over previous
//
#include <hip/hip_runtime.h>
#include <hip/hip_bf16.h>

// DeBERTa layer: B=16,S=512,H=1024,NH=8,HD=128,FF=3072.
// Inputs f32, output f32 (confirmed R4), intermediates bf16, fp32 accum.
// R6: unified MFMA GEMM core (16x16x32_bf16) for QKV/Wo/Wi/Wf + batched QK^T/PV.
#define BB  16
#define SS  512
#define HH  1024
#define NHH 8
#define HDD 128
#define FFF 3072
#define TT  (BB * SS)   // 8192 tokens

typedef __hip_bfloat16 bf16;
typedef short s8v __attribute__((ext_vector_type(8)));   // 8 bf16 bits (4 VGPRs)
typedef float f4v __attribute__((ext_vector_type(4)));   // 4 f32 acc

__device__ __forceinline__ float bf2f(bf16 v) { return __bfloat162float(v); }
__device__ __forceinline__ bf16 f2bf(float f) { return __float2bfloat16(f); }
__device__ __forceinline__ float us2f(unsigned short u) {
  union { unsigned int i; float f; } c; c.i = (unsigned int)u << 16; return c.f;
}

// ---------------- Embedding LayerNorm (f32 in -> bf16 out) ----------------------
__global__ void embed_ln_kernel(const float* __restrict__ x, const float* __restrict__ pos,
                                const float* __restrict__ g, const float* __restrict__ bta,
                                bf16* __restrict__ h) {
  int t = blockIdx.x;
  int s = t & (SS - 1);
  int tid = threadIdx.x;
  const float* xr = x + (size_t)t * HH;
  const float* pr = pos + (size_t)s * HH;
  float vals[4];
  float sum = 0.f;
#pragma unroll
  for (int i = 0; i < 4; i++) {
    int c = tid + i * 256;
    vals[i] = xr[c] + pr[c];
    sum += vals[i];
  }
  __shared__ float red[4];
#pragma unroll
  for (int off = 32; off > 0; off >>= 1) sum += __shfl_down(sum, off, 64);
  if ((tid & 63) == 0) red[tid >> 6] = sum;
  __syncthreads();
  float mean = (red[0] + red[1] + red[2] + red[3]) * (1.f / HH);
  float vsum = 0.f;
#pragma unroll
  for (int i = 0; i < 4; i++) { float d = vals[i] - mean; vsum += d * d; }
  __syncthreads();
#pragma unroll
  for (int off = 32; off > 0; off >>= 1) vsum += __shfl_down(vsum, off, 64);
  if ((tid & 63) == 0) red[tid >> 6] = vsum;
  __syncthreads();
  float rstd = rsqrtf((red[0] + red[1] + red[2] + red[3]) * (1.f / HH) + 1e-7f);
  bf16* hr = h + (size_t)t * HH;
#pragma unroll
  for (int i = 0; i < 4; i++) {
    int c = tid + i * 256;
    hr[c] = f2bf((vals[i] - mean) * rstd * g[c] + bta[c]);
  }
}

// ------- a(bf16)+res(bf16) -> LN -> out (OUT_F32 ? float : bf16) ---------------
template <int OUT_F32>
__global__ void add_ln_kernel(const bf16* __restrict__ a, const bf16* __restrict__ res,
                              const float* __restrict__ g, const float* __restrict__ bta,
                              void* __restrict__ outv) {
  int t = blockIdx.x;
  int tid = threadIdx.x;
  const bf16* ar = a + (size_t)t * HH;
  const bf16* rr = res + (size_t)t * HH;
  float vals[4];
  float sum = 0.f;
#pragma unroll
  for (int i = 0; i < 4; i++) {
    int c = tid + i * 256;
    vals[i] = bf2f(ar[c]) + bf2f(rr[c]);
    sum += vals[i];
  }
  __shared__ float red[4];
#pragma unroll
  for (int off = 32; off > 0; off >>= 1) sum += __shfl_down(sum, off, 64);
  if ((tid & 63) == 0) red[tid >> 6] = sum;
  __syncthreads();
  float mean = (red[0] + red[1] + red[2] + red[3]) * (1.f / HH);
  float vsum = 0.f;
#pragma unroll
  for (int i = 0; i < 4; i++) { float d = vals[i] - mean; vsum += d * d; }
  __syncthreads();
#pragma unroll
  for (int off = 32; off > 0; off >>= 1) vsum += __shfl_down(vsum, off, 64);
  if ((tid & 63) == 0) red[tid >> 6] = vsum;
  __syncthreads();
  float rstd = rsqrtf((red[0] + red[1] + red[2] + red[3]) * (1.f / HH) + 1e-7f);
#pragma unroll
  for (int i = 0; i < 4; i++) {
    int c = tid + i * 256;
    float o = (vals[i] - mean) * rstd * g[c] + bta[c];
    if (OUT_F32)
      ((float*)outv)[(size_t)t * HH + c] = o;
    else
      ((bf16*)outv)[(size_t)t * HH + c] = f2bf(o);
  }
}

// ---- weight convert+transpose: W[K,N] f32 -> Wt[N,K] bf16 ---------------------
__global__ void convert_w_kernel(const float* __restrict__ W, bf16* __restrict__ Wt,
                                 int K, int N) {
  __shared__ float tile[32][33];
  int n0 = blockIdx.x * 32, k0 = blockIdx.y * 32;
#pragma unroll
  for (int it = 0; it < 4; it++) {
    int idx = threadIdx.x + it * 256;
    int ty = idx >> 5, tx = idx & 31;
    tile[ty][tx] = W[(size_t)(k0 + ty) * N + n0 + tx];
  }
  __syncthreads();
#pragma unroll
  for (int it = 0; it < 4; it++) {
    int idx = threadIdx.x + it * 256;
    int ty = idx >> 5, tx = idx & 31;
    Wt[(size_t)(n0 + ty) * K + k0 + tx] = f2bf(tile[tx][ty]);
  }
}

// ---- V transpose per head: v[T,H] -> vt[b,h,dim,key] (bf16) -------------------
__global__ void transpose_v_kernel(const bf16* __restrict__ v, bf16* __restrict__ vt) {
  __shared__ unsigned short tile[32][33];
  int bh = blockIdx.z;
  int s0 = blockIdx.x * 32, d0 = blockIdx.y * 32;
  int b = bh >> 3, hd = bh & 7;
  const unsigned short* vp = (const unsigned short*)v + ((size_t)b * SS) * HH + hd * HDD;
  unsigned short* vtp = (unsigned short*)vt + (size_t)bh * HDD * SS;
#pragma unroll
  for (int it = 0; it < 4; it++) {
    int idx = threadIdx.x + it * 256;
    int ty = idx >> 5, tx = idx & 31;
    tile[ty][tx] = vp[(size_t)(s0 + ty) * HH + d0 + tx];
  }
  __syncthreads();
#pragma unroll
  for (int it = 0; it < 4; it++) {
    int idx = threadIdx.x + it * 256;
    int ty = idx >> 5, tx = idx & 31;
    vtp[(size_t)(d0 + ty) * SS + s0 + tx] = tile[tx][ty];
  }
}

// ---- Unified MFMA GEMM: C[M,N](bf16) = act((A[M,K] @ Bt[N,K]^T + bias)*scale) --
// 128x128 tile, BK=32, 4 waves x (4x4) mfma_f32_16x16x32_bf16 tiles.
// Layouts (verified m89/m91): A-frag A[m=lane&15][k=quad*8+j], B-frag
// B[k=quad*8+j][n=lane&15], C/D row=quad*4+reg col=lane&15.
// LDS rows padded to 40 ushorts (80B) -> 2-way bank conflicts only (free).
// Batched via blockIdx.z = b*8+h with separate b/h strides.
template <int GELU>
__global__ __launch_bounds__(256)
void mfma_gemm_kernel(const bf16* __restrict__ A, int lda, long long sAb, long long sAh,
                      const bf16* __restrict__ Bt, int ldb, long long sBb, long long sBh,
                      const float* __restrict__ bias,
                      bf16* __restrict__ C, int ldc, long long sCb, long long sCh,
                      int M, int N, int K, float scale) {
  __shared__ unsigned short Als[128 * 40];
  __shared__ unsigned short Bls[128 * 40];
  int tid = threadIdx.x;
  int lane = tid & 63, wave = tid >> 6;
  int l15 = lane & 15, quad = lane >> 4;
  int wm = wave & 1, wn = wave >> 1;
  int m0 = blockIdx.y * 128, n0 = blockIdx.x * 128;
  int zb = blockIdx.z >> 3, zh = blockIdx.z & 7;
  const bf16* Ab = A + zb * sAb + zh * sAh;
  const bf16* Bb = Bt + zb * sBb + zh * sBh;
  bf16* Cb = C + zb * sCb + zh * sCh;
  f4v acc[4][4];
#pragma unroll
  for (int i = 0; i < 4; i++)
#pragma unroll
    for (int j = 0; j < 4; j++) acc[i][j] = (f4v){0.f, 0.f, 0.f, 0.f};
  int r0 = tid >> 2;            // staging rows r0, r0+64
  int q8 = (tid & 3) * 8;       // staging col offset (8 bf16 = 16B)
  for (int k0 = 0; k0 < K; k0 += 32) {
    uint4 a0 = *(const uint4*)(Ab + (size_t)(m0 + r0) * lda + k0 + q8);
    uint4 a1 = *(const uint4*)(Ab + (size_t)(m0 + r0 + 64) * lda + k0 + q8);
    uint4 b0 = *(const uint4*)(Bb + (size_t)(n0 + r0) * ldb + k0 + q8);
    uint4 b1 = *(const uint4*)(Bb + (size_t)(n0 + r0 + 64) * ldb + k0 + q8);
    *(uint4*)&Als[r0 * 40 + q8] = a0;
    *(uint4*)&Als[(r0 + 64) * 40 + q8] = a1;
    *(uint4*)&Bls[r0 * 40 + q8] = b0;
    *(uint4*)&Bls[(r0 + 64) * 40 + q8] = b1;
    __syncthreads();
    s8v af[4], bfr[4];
#pragma unroll
    for (int i = 0; i < 4; i++)
      af[i] = *(const s8v*)&Als[(wm * 64 + i * 16 + l15) * 40 + quad * 8];
#pragma unroll
    for (int j = 0; j < 4; j++)
      bfr[j] = *(const s8v*)&Bls[(wn * 64 + j * 16 + l15) * 40 + quad * 8];
#pragma unroll
    for (int i = 0; i < 4; i++)
#pragma unroll
      for (int j = 0; j < 4; j++)
        acc[i][j] = __builtin_amdgcn_mfma_f32_16x16x32_bf16(af[i], bfr[j], acc[i][j], 0, 0, 0);
    __syncthreads();
  }
#pragma unroll
  for (int i = 0; i < 4; i++) {
#pragma unroll
    for (int j = 0; j < 4; j++) {
      int n = n0 + wn * 64 + j * 16 + l15;
      float bval = bias ? bias[n] : 0.f;
#pragma unroll
      for (int r = 0; r < 4; r++) {
        int m = m0 + wm * 64 + i * 16 + quad * 4 + r;
        float v = (acc[i][j][r] + bval) * scale;
        if (GELU) v = 0.5f * v * (1.f + erff(v * 0.70710678118654752f));
        Cb[(size_t)m * ldc + n] = f2bf(v);
      }
    }
  }
}

// ---- softmax over last dim of scores [128*512 rows][512], bf16 in-place -------
__global__ void softmax_kernel(bf16* __restrict__ sc) {
  int wave = threadIdx.x >> 6, lane = threadIdx.x & 63;
  size_t row = (size_t)blockIdx.x * 4 + wave;
  unsigned short* p = (unsigned short*)sc + row * SS + lane * 8;
  union { uint4 u4; unsigned short u[8]; } buf;
  buf.u4 = *(const uint4*)p;
  float v[8];
  float mx = -1e30f;
#pragma unroll
  for (int j = 0; j < 8; j++) { v[j] = us2f(buf.u[j]); mx = fmaxf(mx, v[j]); }
#pragma unroll
  for (int off = 32; off > 0; off >>= 1) mx = fmaxf(mx, __shfl_xor(mx, off));
  float sum = 0.f;
#pragma unroll
  for (int j = 0; j < 8; j++) { v[j] = __expf(v[j] - mx); sum += v[j]; }
#pragma unroll
  for (int off = 32; off > 0; off >>= 1) sum += __shfl_xor(sum, off);
  float inv = 1.f / sum;
  union { uint4 u4; unsigned short u[8]; } obuf;
#pragma unroll
  for (int j = 0; j < 8; j++) {
    bf16 b = f2bf(v[j] * inv);
    obuf.u[j] = *(unsigned short*)&b;
  }
  *(uint4*)p = obuf.u4;
}

// ---------------- launch ----------------
extern "C" void kernel_launch(void* const* d_in, const int* in_sizes, int n_in,
                              void* d_out, int out_size, void* d_ws, size_t ws_size,
                              hipStream_t stream) {
  const float* x     = (const float*)d_in[0];
  const float* pos   = (const float*)d_in[1];
  const float* eg    = (const float*)d_in[2];
  const float* ebeta = (const float*)d_in[3];
  const float* Wq    = (const float*)d_in[4];
  const float* Wk    = (const float*)d_in[5];
  const float* Wv    = (const float*)d_in[6];
  const float* qbias = (const float*)d_in[7];
  const float* vbias = (const float*)d_in[8];
  const float* Wo    = (const float*)d_in[9];
  const float* bo    = (const float*)d_in[10];
  const float* l1g   = (const float*)d_in[11];
  const float* l1b   = (const float*)d_in[12];
  const float* Wi    = (const float*)d_in[13];
  const float* bi    = (const float*)d_in[14];
  const float* Wf    = (const float*)d_in[15];
  const float* bfb   = (const float*)d_in[16];
  const float* l2g   = (const float*)d_in[17];
  const float* l2b   = (const float*)d_in[18];

  // --- workspace (256 MiB): [MiB offsets] ---
  char* w = (char*)d_ws;
  const size_t MB = (size_t)1 << 20;
  bf16* h      = (bf16*)(w + 0 * MB);     // 16
  bf16* q      = (bf16*)(w + 16 * MB);    // 16
  bf16* k      = (bf16*)(w + 32 * MB);    // 16
  bf16* v      = (bf16*)(w + 48 * MB);    // 16
  bf16* ctx    = (bf16*)(w + 64 * MB);    // 16
  bf16* tmp1   = (bf16*)(w + 80 * MB);    // 16
  bf16* attn   = (bf16*)(w + 96 * MB);    // 16
  bf16* scores = (bf16*)(w + 112 * MB);   // 64 [112,176) live: qk->pv
  bf16* ff     = (bf16*)(w + 112 * MB);   // 48 [112,160) live: Wi->Wf (disjoint lifetime)
  bf16* tmp2   = (bf16*)(w + 176 * MB);   // 16
  bf16* vt     = (bf16*)(w + 192 * MB);   // 16
  bf16* Wqt    = (bf16*)(w + 208 * MB);   // 2
  bf16* Wkt    = (bf16*)(w + 210 * MB);   // 2
  bf16* Wvt    = (bf16*)(w + 212 * MB);   // 2
  bf16* Wot    = (bf16*)(w + 214 * MB);   // 2
  bf16* Wit    = (bf16*)(w + 216 * MB);   // 6
  bf16* Wft    = (bf16*)(w + 222 * MB);   // 6 -> ends 228
  float* out   = (float*)d_out;

  const float QSCALE = 0.08838834764831845f;  // 1/sqrt(128), folded into Wq gemm

  embed_ln_kernel<<<TT, 256, 0, stream>>>(x, pos, eg, ebeta, h);

  convert_w_kernel<<<dim3(HH / 32, HH / 32), 256, 0, stream>>>(Wq, Wqt, HH, HH);
  convert_w_kernel<<<dim3(HH / 32, HH / 32), 256, 0, stream>>>(Wk, Wkt, HH, HH);
  convert_w_kernel<<<dim3(HH / 32, HH / 32), 256, 0, stream>>>(Wv, Wvt, HH, HH);
  convert_w_kernel<<<dim3(HH / 32, HH / 32), 256, 0, stream>>>(Wo, Wot, HH, HH);
  convert_w_kernel<<<dim3(FFF / 32, HH / 32), 256, 0, stream>>>(Wi, Wit, HH, FFF);
  convert_w_kernel<<<dim3(HH / 32, FFF / 32), 256, 0, stream>>>(Wf, Wft, FFF, HH);

  // QKV projections: C[8192,1024] = h @ Wt^T
  mfma_gemm_kernel<0><<<dim3(8, 64, 1), 256, 0, stream>>>(
      h, HH, 0, 0, Wqt, HH, 0, 0, qbias, q, HH, 0, 0, TT, HH, HH, QSCALE);
  mfma_gemm_kernel<0><<<dim3(8, 64, 1), 256, 0, stream>>>(
      h, HH, 0, 0, Wkt, HH, 0, 0, nullptr, k, HH, 0, 0, TT, HH, HH, 1.f);
  mfma_gemm_kernel<0><<<dim3(8, 64, 1), 256, 0, stream>>>(
      h, HH, 0, 0, Wvt, HH, 0, 0, vbias, v, HH, 0, 0, TT, HH, HH, 1.f);

  // scores[b,h,512,512] = q_bh @ k_bh^T  (k in [S,HD] is already "Bt" layout)
  mfma_gemm_kernel<0><<<dim3(4, 4, BB * NHH), 256, 0, stream>>>(
      q, HH, (long long)SS * HH, HDD,
      k, HH, (long long)SS * HH, HDD,
      nullptr,
      scores, SS, (long long)NHH * SS * SS, (long long)SS * SS,
      SS, SS, HDD, 1.f);

  softmax_kernel<<<BB * NHH * SS / 4, 256, 0, stream>>>(scores);

  transpose_v_kernel<<<dim3(SS / 32, HDD / 32, BB * NHH), 256, 0, stream>>>(v, vt);

  // ctx_bh[512,128] = probs_bh @ v_bh  (vt[dim][key] is "Bt" layout)
  mfma_gemm_kernel<0><<<dim3(1, 4, BB * NHH), 256, 0, stream>>>(
      scores, SS, (long long)NHH * SS * SS, (long long)SS * SS,
      vt, SS, (long long)NHH * HDD * SS, (long long)HDD * SS,
      nullptr,
      ctx, HH, (long long)SS * HH, HDD,
      SS, HDD, SS, 1.f);

  mfma_gemm_kernel<0><<<dim3(8, 64, 1), 256, 0, stream>>>(
      ctx, HH, 0, 0, Wot, HH, 0, 0, bo, tmp1, HH, 0, 0, TT, HH, HH, 1.f);
  add_ln_kernel<0><<<TT, 256, 0, stream>>>(tmp1, h, l1g, l1b, attn);

  mfma_gemm_kernel<1><<<dim3(24, 64, 1), 256, 0, stream>>>(
      attn, HH, 0, 0, Wit, HH, 0, 0, bi, ff, FFF, 0, 0, TT, FFF, HH, 1.f);
  mfma_gemm_kernel<0><<<dim3(8, 64, 1), 256, 0, stream>>>(
      ff, FFF, 0, 0, Wft, FFF, 0, 0, bfb, tmp2, HH, 0, 0, TT, HH, FFF, 1.f);
  add_ln_kernel<1><<<TT, 256, 0, stream>>>(tmp2, attn, l2g, l2b, out);
}

// Round 7
// 589.642 us; speedup vs baseline: 7.2130x; 1.0378x over previous
//
#include <hip/hip_runtime.h>
#include <hip/hip_bf16.h>

// DeBERTa layer: B=16,S=512,H=1024,NH=8,HD=128,FF=3072.
// Inputs f32, output f32 (confirmed R4), intermediates bf16, fp32 accum.
// R7: m97-style staging — global_load_lds width=16, unpadded LDS (64B rows).
#define BB  16
#define SS  512
#define HH  1024
#define NHH 8
#define HDD 128
#define FFF 3072
#define TT  (BB * SS)   // 8192 tokens

typedef __hip_bfloat16 bf16;
typedef short s8v __attribute__((ext_vector_type(8)));   // 8 bf16 bits (4 VGPRs)
typedef float f4v __attribute__((ext_vector_type(4)));   // 4 f32 acc

__device__ __forceinline__ float bf2f(bf16 v) { return __bfloat162float(v); }
__device__ __forceinline__ bf16 f2bf(float f) { return __float2bfloat16(f); }
__device__ __forceinline__ float us2f(unsigned short u) {
  union { unsigned int i; float f; } c; c.i = (unsigned int)u << 16; return c.f;
}

// async global->LDS, 16B per lane; LDS dest = wave-uniform base + lane*16
__device__ __forceinline__ void gload_lds16(const bf16* g, unsigned short* l) {
  __builtin_amdgcn_global_load_lds(
      (const __attribute__((address_space(1))) unsigned int*)(g),
      (__attribute__((address_space(3))) unsigned int*)(l), 16, 0, 0);
}

// ---------------- Embedding LayerNorm (f32 in -> bf16 out) ----------------------
__global__ void embed_ln_kernel(const float* __restrict__ x, const float* __restrict__ pos,
                                const float* __restrict__ g, const float* __restrict__ bta,
                                bf16* __restrict__ h) {
  int t = blockIdx.x;
  int s = t & (SS - 1);
  int tid = threadIdx.x;
  const float* xr = x + (size_t)t * HH;
  const float* pr = pos + (size_t)s * HH;
  float vals[4];
  float sum = 0.f;
#pragma unroll
  for (int i = 0; i < 4; i++) {
    int c = tid + i * 256;
    vals[i] = xr[c] + pr[c];
    sum += vals[i];
  }
  __shared__ float red[4];
#pragma unroll
  for (int off = 32; off > 0; off >>= 1) sum += __shfl_down(sum, off, 64);
  if ((tid & 63) == 0) red[tid >> 6] = sum;
  __syncthreads();
  float mean = (red[0] + red[1] + red[2] + red[3]) * (1.f / HH);
  float vsum = 0.f;
#pragma unroll
  for (int i = 0; i < 4; i++) { float d = vals[i] - mean; vsum += d * d; }
  __syncthreads();
#pragma unroll
  for (int off = 32; off > 0; off >>= 1) vsum += __shfl_down(vsum, off, 64);
  if ((tid & 63) == 0) red[tid >> 6] = vsum;
  __syncthreads();
  float rstd = rsqrtf((red[0] + red[1] + red[2] + red[3]) * (1.f / HH) + 1e-7f);
  bf16* hr = h + (size_t)t * HH;
#pragma unroll
  for (int i = 0; i < 4; i++) {
    int c = tid + i * 256;
    hr[c] = f2bf((vals[i] - mean) * rstd * g[c] + bta[c]);
  }
}

// ------- a(bf16)+res(bf16) -> LN -> out (OUT_F32 ? float : bf16) ---------------
template <int OUT_F32>
__global__ void add_ln_kernel(const bf16* __restrict__ a, const bf16* __restrict__ res,
                              const float* __restrict__ g, const float* __restrict__ bta,
                              void* __restrict__ outv) {
  int t = blockIdx.x;
  int tid = threadIdx.x;
  const bf16* ar = a + (size_t)t * HH;
  const bf16* rr = res + (size_t)t * HH;
  float vals[4];
  float sum = 0.f;
#pragma unroll
  for (int i = 0; i < 4; i++) {
    int c = tid + i * 256;
    vals[i] = bf2f(ar[c]) + bf2f(rr[c]);
    sum += vals[i];
  }
  __shared__ float red[4];
#pragma unroll
  for (int off = 32; off > 0; off >>= 1) sum += __shfl_down(sum, off, 64);
  if ((tid & 63) == 0) red[tid >> 6] = sum;
  __syncthreads();
  float mean = (red[0] + red[1] + red[2] + red[3]) * (1.f / HH);
  float vsum = 0.f;
#pragma unroll
  for (int i = 0; i < 4; i++) { float d = vals[i] - mean; vsum += d * d; }
  __syncthreads();
#pragma unroll
  for (int off = 32; off > 0; off >>= 1) vsum += __shfl_down(vsum, off, 64);
  if ((tid & 63) == 0) red[tid >> 6] = vsum;
  __syncthreads();
  float rstd = rsqrtf((red[0] + red[1] + red[2] + red[3]) * (1.f / HH) + 1e-7f);
#pragma unroll
  for (int i = 0; i < 4; i++) {
    int c = tid + i * 256;
    float o = (vals[i] - mean) * rstd * g[c] + bta[c];
    if (OUT_F32)
      ((float*)outv)[(size_t)t * HH + c] = o;
    else
      ((bf16*)outv)[(size_t)t * HH + c] = f2bf(o);
  }
}

// ---- weight convert+transpose: W[K,N] f32 -> Wt[N,K] bf16 ---------------------
__global__ void convert_w_kernel(const float* __restrict__ W, bf16* __restrict__ Wt,
                                 int K, int N) {
  __shared__ float tile[32][33];
  int n0 = blockIdx.x * 32, k0 = blockIdx.y * 32;
#pragma unroll
  for (int it = 0; it < 4; it++) {
    int idx = threadIdx.x + it * 256;
    int ty = idx >> 5, tx = idx & 31;
    tile[ty][tx] = W[(size_t)(k0 + ty) * N + n0 + tx];
  }
  __syncthreads();
#pragma unroll
  for (int it = 0; it < 4; it++) {
    int idx = threadIdx.x + it * 256;
    int ty = idx >> 5, tx = idx & 31;
    Wt[(size_t)(n0 + ty) * K + k0 + tx] = f2bf(tile[tx][ty]);
  }
}

// ---- V transpose per head: v[T,H] -> vt[b,h,dim,key] (bf16) -------------------
__global__ void transpose_v_kernel(const bf16* __restrict__ v, bf16* __restrict__ vt) {
  __shared__ unsigned short tile[32][33];
  int bh = blockIdx.z;
  int s0 = blockIdx.x * 32, d0 = blockIdx.y * 32;
  int b = bh >> 3, hd = bh & 7;
  const unsigned short* vp = (const unsigned short*)v + ((size_t)b * SS) * HH + hd * HDD;
  unsigned short* vtp = (unsigned short*)vt + (size_t)bh * HDD * SS;
#pragma unroll
  for (int it = 0; it < 4; it++) {
    int idx = threadIdx.x + it * 256;
    int ty = idx >> 5, tx = idx & 31;
    tile[ty][tx] = vp[(size_t)(s0 + ty) * HH + d0 + tx];
  }
  __syncthreads();
#pragma unroll
  for (int it = 0; it < 4; it++) {
    int idx = threadIdx.x + it * 256;
    int ty = idx >> 5, tx = idx & 31;
    vtp[(size_t)(d0 + ty) * SS + s0 + tx] = tile[tx][ty];
  }
}

// ---- Unified MFMA GEMM: C[M,N](bf16) = act((A[M,K] @ Bt[N,K]^T + bias)*scale) --
// 128x128 tile, BK=32, 4 waves x (4x4) mfma_f32_16x16x32_bf16 tiles.
// m97 staging: global_load_lds width=16, UNPADDED LDS rows (32 ushort = 64B);
// lane l of each wave covers row l/4, 16B chunk l%4 -> LDS off = lane*16 exactly.
// Batched via blockIdx.z = b*8+h with separate b/h strides.
template <int GELU>
__global__ __launch_bounds__(256)
void mfma_gemm_kernel(const bf16* __restrict__ A, int lda, long long sAb, long long sAh,
                      const bf16* __restrict__ Bt, int ldb, long long sBb, long long sBh,
                      const float* __restrict__ bias,
                      bf16* __restrict__ C, int ldc, long long sCb, long long sCh,
                      int M, int N, int K, float scale) {
  __shared__ unsigned short Als[128 * 32];
  __shared__ unsigned short Bls[128 * 32];
  int tid = threadIdx.x;
  int lane = tid & 63, wave = tid >> 6;
  int l15 = lane & 15, quad = lane >> 4;
  int wm = wave & 1, wn = wave >> 1;
  int m0 = blockIdx.y * 128, n0 = blockIdx.x * 128;
  int zb = blockIdx.z >> 3, zh = blockIdx.z & 7;
  const bf16* Ab = A + zb * sAb + zh * sAh;
  const bf16* Bb = Bt + zb * sBb + zh * sBh;
  bf16* Cb = C + zb * sCb + zh * sCh;
  f4v acc[4][4];
#pragma unroll
  for (int i = 0; i < 4; i++)
#pragma unroll
    for (int j = 0; j < 4; j++) acc[i][j] = (f4v){0.f, 0.f, 0.f, 0.f};
  int lrow = lane >> 2;          // 0..15: row within 16-row call slab
  int lcol = (lane & 3) * 8;     // 0,8,16,24: element offset of 16B chunk
  const bf16* Abase = Ab + (size_t)(m0 + wave * 32 + lrow) * lda + lcol;
  const bf16* Bbase = Bb + (size_t)(n0 + wave * 32 + lrow) * ldb + lcol;
  unsigned short* AL0 = &Als[(wave * 32) * 32];
  unsigned short* AL1 = &Als[(wave * 32 + 16) * 32];
  unsigned short* BL0 = &Bls[(wave * 32) * 32];
  unsigned short* BL1 = &Bls[(wave * 32 + 16) * 32];
  for (int k0 = 0; k0 < K; k0 += 32) {
    gload_lds16(Abase + k0, AL0);
    gload_lds16(Abase + k0 + (size_t)16 * lda, AL1);
    gload_lds16(Bbase + k0, BL0);
    gload_lds16(Bbase + k0 + (size_t)16 * ldb, BL1);
    __syncthreads();
    s8v af[4], bfr[4];
#pragma unroll
    for (int i = 0; i < 4; i++)
      af[i] = *(const s8v*)&Als[(wm * 64 + i * 16 + l15) * 32 + quad * 8];
#pragma unroll
    for (int j = 0; j < 4; j++)
      bfr[j] = *(const s8v*)&Bls[(wn * 64 + j * 16 + l15) * 32 + quad * 8];
#pragma unroll
    for (int i = 0; i < 4; i++)
#pragma unroll
      for (int j = 0; j < 4; j++)
        acc[i][j] = __builtin_amdgcn_mfma_f32_16x16x32_bf16(af[i], bfr[j], acc[i][j], 0, 0, 0);
    __syncthreads();
  }
#pragma unroll
  for (int i = 0; i < 4; i++) {
#pragma unroll
    for (int j = 0; j < 4; j++) {
      int n = n0 + wn * 64 + j * 16 + l15;
      float bval = bias ? bias[n] : 0.f;
#pragma unroll
      for (int r = 0; r < 4; r++) {
        int m = m0 + wm * 64 + i * 16 + quad * 4 + r;
        float v = (acc[i][j][r] + bval) * scale;
        if (GELU) v = 0.5f * v * (1.f + erff(v * 0.70710678118654752f));
        Cb[(size_t)m * ldc + n] = f2bf(v);
      }
    }
  }
}

// ---- softmax over last dim of scores [128*512 rows][512], bf16 in-place -------
__global__ void softmax_kernel(bf16* __restrict__ sc) {
  int wave = threadIdx.x >> 6, lane = threadIdx.x & 63;
  size_t row = (size_t)blockIdx.x * 4 + wave;
  unsigned short* p = (unsigned short*)sc + row * SS + lane * 8;
  union { uint4 u4; unsigned short u[8]; } buf;
  buf.u4 = *(const uint4*)p;
  float v[8];
  float mx = -1e30f;
#pragma unroll
  for (int j = 0; j < 8; j++) { v[j] = us2f(buf.u[j]); mx = fmaxf(mx, v[j]); }
#pragma unroll
  for (int off = 32; off > 0; off >>= 1) mx = fmaxf(mx, __shfl_xor(mx, off));
  float sum = 0.f;
#pragma unroll
  for (int j = 0; j < 8; j++) { v[j] = __expf(v[j] - mx); sum += v[j]; }
#pragma unroll
  for (int off = 32; off > 0; off >>= 1) sum += __shfl_xor(sum, off);
  float inv = 1.f / sum;
  union { uint4 u4; unsigned short u[8]; } obuf;
#pragma unroll
  for (int j = 0; j < 8; j++) {
    bf16 b = f2bf(v[j] * inv);
    obuf.u[j] = *(unsigned short*)&b;
  }
  *(uint4*)p = obuf.u4;
}

// ---------------- launch ----------------
extern "C" void kernel_launch(void* const* d_in, const int* in_sizes, int n_in,
                              void* d_out, int out_size, void* d_ws, size_t ws_size,
                              hipStream_t stream) {
  const float* x     = (const float*)d_in[0];
  const float* pos   = (const float*)d_in[1];
  const float* eg    = (const float*)d_in[2];
  const float* ebeta = (const float*)d_in[3];
  const float* Wq    = (const float*)d_in[4];
  const float* Wk    = (const float*)d_in[5];
  const float* Wv    = (const float*)d_in[6];
  const float* qbias = (const float*)d_in[7];
  const float* vbias = (const float*)d_in[8];
  const float* Wo    = (const float*)d_in[9];
  const float* bo    = (const float*)d_in[10];
  const float* l1g   = (const float*)d_in[11];
  const float* l1b   = (const float*)d_in[12];
  const float* Wi    = (const float*)d_in[13];
  const float* bi    = (const float*)d_in[14];
  const float* Wf    = (const float*)d_in[15];
  const float* bfb   = (const float*)d_in[16];
  const float* l2g   = (const float*)d_in[17];
  const float* l2b   = (const float*)d_in[18];

  // --- workspace (256 MiB): [MiB offsets] ---
  char* w = (char*)d_ws;
  const size_t MB = (size_t)1 << 20;
  bf16* h      = (bf16*)(w + 0 * MB);     // 16
  bf16* q      = (bf16*)(w + 16 * MB);    // 16
  bf16* k      = (bf16*)(w + 32 * MB);    // 16
  bf16* v      = (bf16*)(w + 48 * MB);    // 16
  bf16* ctx    = (bf16*)(w + 64 * MB);    // 16
  bf16* tmp1   = (bf16*)(w + 80 * MB);    // 16
  bf16* attn   = (bf16*)(w + 96 * MB);    // 16
  bf16* scores = (bf16*)(w + 112 * MB);   // 64 [112,176) live: qk->pv
  bf16* ff     = (bf16*)(w + 112 * MB);   // 48 [112,160) live: Wi->Wf (disjoint lifetime)
  bf16* tmp2   = (bf16*)(w + 176 * MB);   // 16
  bf16* vt     = (bf16*)(w + 192 * MB);   // 16
  bf16* Wqt    = (bf16*)(w + 208 * MB);   // 2
  bf16* Wkt    = (bf16*)(w + 210 * MB);   // 2
  bf16* Wvt    = (bf16*)(w + 212 * MB);   // 2
  bf16* Wot    = (bf16*)(w + 214 * MB);   // 2
  bf16* Wit    = (bf16*)(w + 216 * MB);   // 6
  bf16* Wft    = (bf16*)(w + 222 * MB);   // 6 -> ends 228
  float* out   = (float*)d_out;

  const float QSCALE = 0.08838834764831845f;  // 1/sqrt(128), folded into Wq gemm

  embed_ln_kernel<<<TT, 256, 0, stream>>>(x, pos, eg, ebeta, h);

  convert_w_kernel<<<dim3(HH / 32, HH / 32), 256, 0, stream>>>(Wq, Wqt, HH, HH);
  convert_w_kernel<<<dim3(HH / 32, HH / 32), 256, 0, stream>>>(Wk, Wkt, HH, HH);
  convert_w_kernel<<<dim3(HH / 32, HH / 32), 256, 0, stream>>>(Wv, Wvt, HH, HH);
  convert_w_kernel<<<dim3(HH / 32, HH / 32), 256, 0, stream>>>(Wo, Wot, HH, HH);
  convert_w_kernel<<<dim3(FFF / 32, HH / 32), 256, 0, stream>>>(Wi, Wit, HH, FFF);
  convert_w_kernel<<<dim3(HH / 32, FFF / 32), 256, 0, stream>>>(Wf, Wft, FFF, HH);

  // QKV projections: C[8192,1024] = h @ Wt^T
  mfma_gemm_kernel<0><<<dim3(8, 64, 1), 256, 0, stream>>>(
      h, HH, 0, 0, Wqt, HH, 0, 0, qbias, q, HH, 0, 0, TT, HH, HH, QSCALE);
  mfma_gemm_kernel<0><<<dim3(8, 64, 1), 256, 0, stream>>>(
      h, HH, 0, 0, Wkt, HH, 0, 0, nullptr, k, HH, 0, 0, TT, HH, HH, 1.f);
  mfma_gemm_kernel<0><<<dim3(8, 64, 1), 256, 0, stream>>>(
      h, HH, 0, 0, Wvt, HH, 0, 0, vbias, v, HH, 0, 0, TT, HH, HH, 1.f);

  // scores[b,h,512,512] = q_bh @ k_bh^T  (k in [S,HD] is already "Bt" layout)
  mfma_gemm_kernel<0><<<dim3(4, 4, BB * NHH), 256, 0, stream>>>(
      q, HH, (long long)SS * HH, HDD,
      k, HH, (long long)SS * HH, HDD,
      nullptr,
      scores, SS, (long long)NHH * SS * SS, (long long)SS * SS,
      SS, SS, HDD, 1.f);

  softmax_kernel<<<BB * NHH * SS / 4, 256, 0, stream>>>(scores);

  transpose_v_kernel<<<dim3(SS / 32, HDD / 32, BB * NHH), 256, 0, stream>>>(v, vt);

  // ctx_bh[512,128] = probs_bh @ v_bh  (vt[dim][key] is "Bt" layout)
  mfma_gemm_kernel<0><<<dim3(1, 4, BB * NHH), 256, 0, stream>>>(
      scores, SS, (long long)NHH * SS * SS, (long long)SS * SS,
      vt, SS, (long long)NHH * HDD * SS, (long long)HDD * SS,
      nullptr,
      ctx, HH, (long long)SS * HH, HDD,
      SS, HDD, SS, 1.f);

  mfma_gemm_kernel<0><<<dim3(8, 64, 1), 256, 0, stream>>>(
      ctx, HH, 0, 0, Wot, HH, 0, 0, bo, tmp1, HH, 0, 0, TT, HH, HH, 1.f);
  add_ln_kernel<0><<<TT, 256, 0, stream>>>(tmp1, h, l1g, l1b, attn);

  mfma_gemm_kernel<1><<<dim3(24, 64, 1), 256, 0, stream>>>(
      attn, HH, 0, 0, Wit, HH, 0, 0, bi, ff, FFF, 0, 0, TT, FFF, HH, 1.f);
  mfma_gemm_kernel<0><<<dim3(8, 64, 1), 256, 0, stream>>>(
      ff, FFF, 0, 0, Wft, FFF, 0, 0, bfb, tmp2, HH, 0, 0, TT, HH, FFF, 1.f);
  add_ln_kernel<1><<<TT, 256, 0, stream>>>(tmp2, attn, l2g, l2b, out);
}

// Round 8
// 537.597 us; speedup vs baseline: 7.9113x; 1.0968x over previous
//
#include <hip/hip_runtime.h>
#include <hip/hip_bf16.h>

// DeBERTa layer: B=16,S=512,H=1024,NH=8,HD=128,FF=3072.
// Inputs f32, output f32 (confirmed R4), intermediates bf16, fp32 accum.
// R8: explicit software-pipelined register staging (R7's global_load_lds
// regressed: vmcnt(0) barrier drain kills prefetch) + fused QKV GEMM.
#define BB  16
#define SS  512
#define HH  1024
#define NHH 8
#define HDD 128
#define FFF 3072
#define TT  (BB * SS)   // 8192 tokens

typedef __hip_bfloat16 bf16;
typedef short s8v __attribute__((ext_vector_type(8)));   // 8 bf16 bits (4 VGPRs)
typedef float f4v __attribute__((ext_vector_type(4)));   // 4 f32 acc

__device__ __forceinline__ float bf2f(bf16 v) { return __bfloat162float(v); }
__device__ __forceinline__ bf16 f2bf(float f) { return __float2bfloat16(f); }
__device__ __forceinline__ float us2f(unsigned short u) {
  union { unsigned int i; float f; } c; c.i = (unsigned int)u << 16; return c.f;
}

// ---------------- Embedding LayerNorm (f32 in -> bf16 out) ----------------------
__global__ void embed_ln_kernel(const float* __restrict__ x, const float* __restrict__ pos,
                                const float* __restrict__ g, const float* __restrict__ bta,
                                bf16* __restrict__ h) {
  int t = blockIdx.x;
  int s = t & (SS - 1);
  int tid = threadIdx.x;
  const float* xr = x + (size_t)t * HH;
  const float* pr = pos + (size_t)s * HH;
  float vals[4];
  float sum = 0.f;
#pragma unroll
  for (int i = 0; i < 4; i++) {
    int c = tid + i * 256;
    vals[i] = xr[c] + pr[c];
    sum += vals[i];
  }
  __shared__ float red[4];
#pragma unroll
  for (int off = 32; off > 0; off >>= 1) sum += __shfl_down(sum, off, 64);
  if ((tid & 63) == 0) red[tid >> 6] = sum;
  __syncthreads();
  float mean = (red[0] + red[1] + red[2] + red[3]) * (1.f / HH);
  float vsum = 0.f;
#pragma unroll
  for (int i = 0; i < 4; i++) { float d = vals[i] - mean; vsum += d * d; }
  __syncthreads();
#pragma unroll
  for (int off = 32; off > 0; off >>= 1) vsum += __shfl_down(vsum, off, 64);
  if ((tid & 63) == 0) red[tid >> 6] = vsum;
  __syncthreads();
  float rstd = rsqrtf((red[0] + red[1] + red[2] + red[3]) * (1.f / HH) + 1e-7f);
  bf16* hr = h + (size_t)t * HH;
#pragma unroll
  for (int i = 0; i < 4; i++) {
    int c = tid + i * 256;
    hr[c] = f2bf((vals[i] - mean) * rstd * g[c] + bta[c]);
  }
}

// ------- a(bf16)+res(bf16) -> LN -> out (OUT_F32 ? float : bf16) ---------------
template <int OUT_F32>
__global__ void add_ln_kernel(const bf16* __restrict__ a, const bf16* __restrict__ res,
                              const float* __restrict__ g, const float* __restrict__ bta,
                              void* __restrict__ outv) {
  int t = blockIdx.x;
  int tid = threadIdx.x;
  const bf16* ar = a + (size_t)t * HH;
  const bf16* rr = res + (size_t)t * HH;
  float vals[4];
  float sum = 0.f;
#pragma unroll
  for (int i = 0; i < 4; i++) {
    int c = tid + i * 256;
    vals[i] = bf2f(ar[c]) + bf2f(rr[c]);
    sum += vals[i];
  }
  __shared__ float red[4];
#pragma unroll
  for (int off = 32; off > 0; off >>= 1) sum += __shfl_down(sum, off, 64);
  if ((tid & 63) == 0) red[tid >> 6] = sum;
  __syncthreads();
  float mean = (red[0] + red[1] + red[2] + red[3]) * (1.f / HH);
  float vsum = 0.f;
#pragma unroll
  for (int i = 0; i < 4; i++) { float d = vals[i] - mean; vsum += d * d; }
  __syncthreads();
#pragma unroll
  for (int off = 32; off > 0; off >>= 1) vsum += __shfl_down(vsum, off, 64);
  if ((tid & 63) == 0) red[tid >> 6] = vsum;
  __syncthreads();
  float rstd = rsqrtf((red[0] + red[1] + red[2] + red[3]) * (1.f / HH) + 1e-7f);
#pragma unroll
  for (int i = 0; i < 4; i++) {
    int c = tid + i * 256;
    float o = (vals[i] - mean) * rstd * g[c] + bta[c];
    if (OUT_F32)
      ((float*)outv)[(size_t)t * HH + c] = o;
    else
      ((bf16*)outv)[(size_t)t * HH + c] = f2bf(o);
  }
}

// ---- weight convert+transpose: W[K,N] f32 -> Wt[N,K] bf16 (K fixed per call) --
__global__ void convert_w_kernel(const float* __restrict__ W, bf16* __restrict__ Wt,
                                 int K, int N) {
  __shared__ float tile[32][33];
  int n0 = blockIdx.x * 32, k0 = blockIdx.y * 32;
#pragma unroll
  for (int it = 0; it < 4; it++) {
    int idx = threadIdx.x + it * 256;
    int ty = idx >> 5, tx = idx & 31;
    tile[ty][tx] = W[(size_t)(k0 + ty) * N + n0 + tx];
  }
  __syncthreads();
#pragma unroll
  for (int it = 0; it < 4; it++) {
    int idx = threadIdx.x + it * 256;
    int ty = idx >> 5, tx = idx & 31;
    Wt[(size_t)(n0 + ty) * K + k0 + tx] = f2bf(tile[tx][ty]);
  }
}

// ---- concat qkv bias: [qbias | 0 | vbias] (f32) -------------------------------
__global__ void build_qkv_bias_kernel(const float* __restrict__ qb,
                                      const float* __restrict__ vb,
                                      float* __restrict__ o) {
  int i = blockIdx.x * 256 + threadIdx.x;  // 0..3071
  float v = 0.f;
  if (i < HH) v = qb[i];
  else if (i >= 2 * HH) v = vb[i - 2 * HH];
  o[i] = v;
}

// ---- V transpose per head: qkv v-cols -> vt[b,h,dim,key] (bf16) ---------------
__global__ void transpose_v_kernel(const bf16* __restrict__ v, bf16* __restrict__ vt) {
  __shared__ unsigned short tile[32][33];
  int bh = blockIdx.z;
  int s0 = blockIdx.x * 32, d0 = blockIdx.y * 32;
  int b = bh >> 3, hd = bh & 7;
  const unsigned short* vp = (const unsigned short*)v + ((size_t)b * SS) * (3 * HH) + hd * HDD;
  unsigned short* vtp = (unsigned short*)vt + (size_t)bh * HDD * SS;
#pragma unroll
  for (int it = 0; it < 4; it++) {
    int idx = threadIdx.x + it * 256;
    int ty = idx >> 5, tx = idx & 31;
    tile[ty][tx] = vp[(size_t)(s0 + ty) * (3 * HH) + d0 + tx];
  }
  __syncthreads();
#pragma unroll
  for (int it = 0; it < 4; it++) {
    int idx = threadIdx.x + it * 256;
    int ty = idx >> 5, tx = idx & 31;
    vtp[(size_t)(d0 + ty) * SS + s0 + tx] = tile[tx][ty];
  }
}

// ---- Unified MFMA GEMM: C[M,N](bf16) = act((A[M,K] @ Bt[N,K]^T + bias)*scale) --
// 128x128 tile, BK=32, 4 waves x (4x4) mfma_f32_16x16x32_bf16 tiles.
// Explicit 2-stage pipeline: regs(k0) -> ds_write -> barrier -> issue loads(k0+32)
// -> ds_read frags -> MFMA -> barrier. Next tile is in flight during MFMAs.
// LDS rows padded to 40 ushorts (80B): 2-way conflicts only (free, m136).
// Batched via blockIdx.z = b*8+h with separate b/h strides.
template <int GELU>
__global__ __launch_bounds__(256)
void mfma_gemm_kernel(const bf16* __restrict__ A, int lda, long long sAb, long long sAh,
                      const bf16* __restrict__ Bt, int ldb, long long sBb, long long sBh,
                      const float* __restrict__ bias,
                      bf16* __restrict__ C, int ldc, long long sCb, long long sCh,
                      int M, int N, int K, float scale) {
  __shared__ unsigned short Als[128 * 40];
  __shared__ unsigned short Bls[128 * 40];
  int tid = threadIdx.x;
  int lane = tid & 63, wave = tid >> 6;
  int l15 = lane & 15, quad = lane >> 4;
  int wm = wave & 1, wn = wave >> 1;
  int m0 = blockIdx.y * 128, n0 = blockIdx.x * 128;
  int zb = blockIdx.z >> 3, zh = blockIdx.z & 7;
  const bf16* Ab = A + zb * sAb + zh * sAh;
  const bf16* Bb = Bt + zb * sBb + zh * sBh;
  bf16* Cb = C + zb * sCb + zh * sCh;
  f4v acc[4][4];
#pragma unroll
  for (int i = 0; i < 4; i++)
#pragma unroll
    for (int j = 0; j < 4; j++) acc[i][j] = (f4v){0.f, 0.f, 0.f, 0.f};
  int r0 = tid >> 2;            // 0..63: staging rows r0, r0+64
  int q8 = (tid & 3) * 8;       // 16B chunk offset within 32-elem row
  const bf16* Ap0 = Ab + (size_t)(m0 + r0) * lda + q8;
  const bf16* Ap1 = Ab + (size_t)(m0 + r0 + 64) * lda + q8;
  const bf16* Bp0 = Bb + (size_t)(n0 + r0) * ldb + q8;
  const bf16* Bp1 = Bb + (size_t)(n0 + r0 + 64) * ldb + q8;
  uint4 a0 = *(const uint4*)(Ap0);
  uint4 a1 = *(const uint4*)(Ap1);
  uint4 b0 = *(const uint4*)(Bp0);
  uint4 b1 = *(const uint4*)(Bp1);
  for (int k0 = 0; k0 < K; k0 += 32) {
    *(uint4*)&Als[r0 * 40 + q8] = a0;
    *(uint4*)&Als[(r0 + 64) * 40 + q8] = a1;
    *(uint4*)&Bls[r0 * 40 + q8] = b0;
    *(uint4*)&Bls[(r0 + 64) * 40 + q8] = b1;
    __syncthreads();
    int kn = k0 + 32;
    if (kn < K) {           // issue next tile's loads; in flight during MFMAs
      a0 = *(const uint4*)(Ap0 + kn);
      a1 = *(const uint4*)(Ap1 + kn);
      b0 = *(const uint4*)(Bp0 + kn);
      b1 = *(const uint4*)(Bp1 + kn);
    }
    s8v af[4], bfr[4];
#pragma unroll
    for (int i = 0; i < 4; i++)
      af[i] = *(const s8v*)&Als[(wm * 64 + i * 16 + l15) * 40 + quad * 8];
#pragma unroll
    for (int j = 0; j < 4; j++)
      bfr[j] = *(const s8v*)&Bls[(wn * 64 + j * 16 + l15) * 40 + quad * 8];
#pragma unroll
    for (int i = 0; i < 4; i++)
#pragma unroll
      for (int j = 0; j < 4; j++)
        acc[i][j] = __builtin_amdgcn_mfma_f32_16x16x32_bf16(af[i], bfr[j], acc[i][j], 0, 0, 0);
    __syncthreads();
  }
#pragma unroll
  for (int i = 0; i < 4; i++) {
#pragma unroll
    for (int j = 0; j < 4; j++) {
      int n = n0 + wn * 64 + j * 16 + l15;
      float bval = bias ? bias[n] : 0.f;
#pragma unroll
      for (int r = 0; r < 4; r++) {
        int m = m0 + wm * 64 + i * 16 + quad * 4 + r;
        float v = (acc[i][j][r] + bval) * scale;
        if (GELU) v = 0.5f * v * (1.f + erff(v * 0.70710678118654752f));
        Cb[(size_t)m * ldc + n] = f2bf(v);
      }
    }
  }
}

// ---- softmax over last dim of scores [128*512 rows][512], bf16 in-place -------
__global__ void softmax_kernel(bf16* __restrict__ sc) {
  int wave = threadIdx.x >> 6, lane = threadIdx.x & 63;
  size_t row = (size_t)blockIdx.x * 4 + wave;
  unsigned short* p = (unsigned short*)sc + row * SS + lane * 8;
  union { uint4 u4; unsigned short u[8]; } buf;
  buf.u4 = *(const uint4*)p;
  float v[8];
  float mx = -1e30f;
#pragma unroll
  for (int j = 0; j < 8; j++) { v[j] = us2f(buf.u[j]); mx = fmaxf(mx, v[j]); }
#pragma unroll
  for (int off = 32; off > 0; off >>= 1) mx = fmaxf(mx, __shfl_xor(mx, off));
  float sum = 0.f;
#pragma unroll
  for (int j = 0; j < 8; j++) { v[j] = __expf(v[j] - mx); sum += v[j]; }
#pragma unroll
  for (int off = 32; off > 0; off >>= 1) sum += __shfl_xor(sum, off);
  float inv = 1.f / sum;
  union { uint4 u4; unsigned short u[8]; } obuf;
#pragma unroll
  for (int j = 0; j < 8; j++) {
    bf16 b = f2bf(v[j] * inv);
    obuf.u[j] = *(unsigned short*)&b;
  }
  *(uint4*)p = obuf.u4;
}

// ---------------- launch ----------------
extern "C" void kernel_launch(void* const* d_in, const int* in_sizes, int n_in,
                              void* d_out, int out_size, void* d_ws, size_t ws_size,
                              hipStream_t stream) {
  const float* x     = (const float*)d_in[0];
  const float* pos   = (const float*)d_in[1];
  const float* eg    = (const float*)d_in[2];
  const float* ebeta = (const float*)d_in[3];
  const float* Wq    = (const float*)d_in[4];
  const float* Wk    = (const float*)d_in[5];
  const float* Wv    = (const float*)d_in[6];
  const float* qbias = (const float*)d_in[7];
  const float* vbias = (const float*)d_in[8];
  const float* Wo    = (const float*)d_in[9];
  const float* bo    = (const float*)d_in[10];
  const float* l1g   = (const float*)d_in[11];
  const float* l1b   = (const float*)d_in[12];
  const float* Wi    = (const float*)d_in[13];
  const float* bi    = (const float*)d_in[14];
  const float* Wf    = (const float*)d_in[15];
  const float* bfb   = (const float*)d_in[16];
  const float* l2g   = (const float*)d_in[17];
  const float* l2b   = (const float*)d_in[18];

  // --- workspace (256 MiB): [MiB offsets] ---
  char* w = (char*)d_ws;
  const size_t MB = (size_t)1 << 20;
  bf16* h      = (bf16*)(w + 0 * MB);     // 16
  bf16* qkv    = (bf16*)(w + 16 * MB);    // 48: [T][3H] fused q|k|v
  bf16* ctx    = (bf16*)(w + 64 * MB);    // 16
  bf16* tmp1   = (bf16*)(w + 80 * MB);    // 16
  bf16* attn   = (bf16*)(w + 96 * MB);    // 16
  bf16* scores = (bf16*)(w + 112 * MB);   // 64 [112,176) live: qk->pv
  bf16* ff     = (bf16*)(w + 112 * MB);   // 48 [112,160) live: Wi->Wf (disjoint)
  bf16* tmp2   = (bf16*)(w + 176 * MB);   // 16
  bf16* vt     = (bf16*)(w + 192 * MB);   // 16
  bf16* Wqkvt  = (bf16*)(w + 208 * MB);   // 6: [3H][H] packed q|k|v rows
  bf16* Wot    = (bf16*)(w + 214 * MB);   // 2
  bf16* Wit    = (bf16*)(w + 216 * MB);   // 6
  bf16* Wft    = (bf16*)(w + 222 * MB);   // 6
  float* qkvb  = (float*)(w + 228 * MB);  // 12 KB
  float* out   = (float*)d_out;

  const float QSCALE = 0.08838834764831845f;  // 1/sqrt(128), applied in QK epilogue

  embed_ln_kernel<<<TT, 256, 0, stream>>>(x, pos, eg, ebeta, h);

  convert_w_kernel<<<dim3(HH / 32, HH / 32), 256, 0, stream>>>(Wq, Wqkvt, HH, HH);
  convert_w_kernel<<<dim3(HH / 32, HH / 32), 256, 0, stream>>>(Wk, Wqkvt + (size_t)HH * HH, HH, HH);
  convert_w_kernel<<<dim3(HH / 32, HH / 32), 256, 0, stream>>>(Wv, Wqkvt + (size_t)2 * HH * HH, HH, HH);
  convert_w_kernel<<<dim3(HH / 32, HH / 32), 256, 0, stream>>>(Wo, Wot, HH, HH);
  convert_w_kernel<<<dim3(FFF / 32, HH / 32), 256, 0, stream>>>(Wi, Wit, HH, FFF);
  convert_w_kernel<<<dim3(HH / 32, FFF / 32), 256, 0, stream>>>(Wf, Wft, FFF, HH);
  build_qkv_bias_kernel<<<12, 256, 0, stream>>>(qbias, vbias, qkvb);

  // fused QKV: qkv[8192,3072] = h @ Wqkvt^T + qkvb
  mfma_gemm_kernel<0><<<dim3(24, 64, 1), 256, 0, stream>>>(
      h, HH, 0, 0, Wqkvt, HH, 0, 0, qkvb, qkv, 3 * HH, 0, 0, TT, 3 * HH, HH, 1.f);

  // scores[b,h,512,512] = (q_bh @ k_bh^T) * QSCALE  (k cols of qkv act as Bt)
  mfma_gemm_kernel<0><<<dim3(4, 4, BB * NHH), 256, 0, stream>>>(
      qkv, 3 * HH, (long long)SS * 3 * HH, HDD,
      qkv + HH, 3 * HH, (long long)SS * 3 * HH, HDD,
      nullptr,
      scores, SS, (long long)NHH * SS * SS, (long long)SS * SS,
      SS, SS, HDD, QSCALE);

  softmax_kernel<<<BB * NHH * SS / 4, 256, 0, stream>>>(scores);

  transpose_v_kernel<<<dim3(SS / 32, HDD / 32, BB * NHH), 256, 0, stream>>>(qkv + 2 * HH, vt);

  // ctx_bh[512,128] = probs_bh @ v_bh  (vt[dim][key] is Bt layout)
  mfma_gemm_kernel<0><<<dim3(1, 4, BB * NHH), 256, 0, stream>>>(
      scores, SS, (long long)NHH * SS * SS, (long long)SS * SS,
      vt, SS, (long long)NHH * HDD * SS, (long long)HDD * SS,
      nullptr,
      ctx, HH, (long long)SS * HH, HDD,
      SS, HDD, SS, 1.f);

  mfma_gemm_kernel<0><<<dim3(8, 64, 1), 256, 0, stream>>>(
      ctx, HH, 0, 0, Wot, HH, 0, 0, bo, tmp1, HH, 0, 0, TT, HH, HH, 1.f);
  add_ln_kernel<0><<<TT, 256, 0, stream>>>(tmp1, h, l1g, l1b, attn);

  mfma_gemm_kernel<1><<<dim3(24, 64, 1), 256, 0, stream>>>(
      attn, HH, 0, 0, Wit, HH, 0, 0, bi, ff, FFF, 0, 0, TT, FFF, HH, 1.f);
  mfma_gemm_kernel<0><<<dim3(8, 64, 1), 256, 0, stream>>>(
      ff, FFF, 0, 0, Wft, FFF, 0, 0, bfb, tmp2, HH, 0, 0, TT, HH, FFF, 1.f);
  add_ln_kernel<1><<<TT, 256, 0, stream>>>(tmp2, attn, l2g, l2b, out);
}